// Round 1
// baseline (1198.187 us; speedup 1.0000x reference)
//
#include <hip/hip_runtime.h>

#define NSEG 128
#define BB 2
#define CC 768
#define HP 28
#define WP 28
#define HI 392
#define WI 392
#define NPIX (HI*WI)        // 153664
#define NPIX4 (NPIX/4)      // 38416
#define CH_PER_BLK 128

// Pack clamped segment ids to uint8, 4 pixels/thread.
__global__ void pid_kernel(const int* __restrict__ mask, unsigned int* __restrict__ sb) {
    int g = blockIdx.x * blockDim.x + threadIdx.x;
    if (g >= BB * NPIX4) return;
    int4 m = ((const int4*)mask)[g];
    unsigned int s0 = (unsigned int)min(max(m.x, 0), NSEG - 1);
    unsigned int s1 = (unsigned int)min(max(m.y, 0), NSEG - 1);
    unsigned int s2 = (unsigned int)min(max(m.z, 0), NSEG - 1);
    unsigned int s3 = (unsigned int)min(max(m.w, 0), NSEG - 1);
    sb[g] = s0 | (s1 << 8) | (s2 << 16) | (s3 << 24);
}

// One block per patch cell; accumulate feature vector into transposed sums[b][c][s].
__global__ void accum_kernel(const float* __restrict__ F, const int* __restrict__ mask,
                             float* __restrict__ sums, float* __restrict__ counts) {
    int cell = blockIdx.x;                   // 0 .. BB*HP*WP-1
    int b = cell / (HP * WP);
    int rem = cell - b * (HP * WP);
    int hp = rem / WP;
    int wp = rem - hp * WP;
    // ih = hp*HI/HP = hp*14 exactly; iw = wp*14
    int m = mask[(size_t)b * NPIX + (hp * 14) * WI + (wp * 14)];
    int s = min(max(m, 0), NSEG - 1);
    for (int c = threadIdx.x; c < CC; c += blockDim.x) {
        float v = F[((b * CC + c) * HP + hp) * WP + wp];
        atomicAdd(&sums[(size_t)(b * CC + c) * NSEG + s], v);
    }
    if (threadIdx.x == 0) atomicAdd(&counts[b * NSEG + s], 1.0f);
}

// In-place divide: avg[b][c][s] = count>0 ? sum/count : 0
__global__ void div_kernel(float* __restrict__ sums, const float* __restrict__ counts) {
    int i = blockIdx.x * blockDim.x + threadIdx.x;   // < BB*CC*NSEG
    int b = i / (CC * NSEG);
    int s = i & (NSEG - 1);
    float cnt = counts[b * NSEG + s];
    float v = sums[i];
    sums[i] = (cnt > 0.0f) ? (v / cnt) : 0.0f;
}

// Paint: each thread owns 4 consecutive pixels (one float4 store per channel),
// loops over CH_PER_BLK channels. Segment ids held in registers; avg slice
// (512 B per (b,c)) stays L1-hot.
__global__ __launch_bounds__(256) void paint_kernel(const float* __restrict__ avg,
                                                    const unsigned int* __restrict__ sb,
                                                    float* __restrict__ out) {
    int b = blockIdx.z;
    int g = blockIdx.x * blockDim.x + threadIdx.x;   // float4 group within batch
    if (g >= NPIX4) return;
    unsigned int packed = sb[(size_t)b * NPIX4 + g];
    int s0 = packed & 255;
    int s1 = (packed >> 8) & 255;
    int s2 = (packed >> 16) & 255;
    int s3 = (packed >> 24) & 255;
    int c0 = blockIdx.y * CH_PER_BLK;
    const float* tbl = avg + (size_t)(b * CC + c0) * NSEG;
    float4* outp = (float4*)out + (size_t)(b * CC + c0) * NPIX4 + g;
    #pragma unroll 4
    for (int i = 0; i < CH_PER_BLK; ++i) {
        const float* t = tbl + (size_t)i * NSEG;
        float4 v = make_float4(t[s0], t[s1], t[s2], t[s3]);
        outp[(size_t)i * NPIX4] = v;
    }
}

extern "C" void kernel_launch(void* const* d_in, const int* in_sizes, int n_in,
                              void* d_out, int out_size, void* d_ws, size_t ws_size,
                              hipStream_t stream) {
    const float* F = (const float*)d_in[0];
    const int* mask = (const int*)d_in[1];
    float* out = (float*)d_out;

    float* sums = (float*)d_ws;                       // BB*CC*NSEG floats (786,432 B)
    float* counts = sums + BB * CC * NSEG;            // BB*NSEG floats (1,024 B)
    unsigned int* sb = (unsigned int*)(counts + BB * NSEG); // BB*NPIX4 words (307,328 B)

    // Zero sums + counts (ws is poisoned each call).
    hipMemsetAsync(d_ws, 0, (size_t)(BB * CC * NSEG + BB * NSEG) * sizeof(float), stream);

    int ngroups = BB * NPIX4;                                   // 76,832
    pid_kernel<<<(ngroups + 255) / 256, 256, 0, stream>>>(mask, sb);
    accum_kernel<<<BB * HP * WP, 256, 0, stream>>>(F, mask, sums, counts);
    div_kernel<<<(BB * CC * NSEG) / 256, 256, 0, stream>>>(sums, counts);
    paint_kernel<<<dim3((NPIX4 + 255) / 256, CC / CH_PER_BLK, BB), 256, 0, stream>>>(sums, sb, out);
}